// Round 5
// baseline (241.351 us; speedup 1.0000x reference)
//
#include <hip/hip_runtime.h>
#include <hip/hip_cooperative_groups.h>
#include <math.h>

namespace cg = cooperative_groups;

#define NPTS    32
#define UNITS   64
#define PTOT    40000
#define NPAIRS  (PTOT / 2)          // 20000
#define GBLOCKS 1000
#define WPB     4                   // waves per block (256 threads)
#define TOTW    (GBLOCKS * WPB)     // 4000 waves
#define PPW     (NPAIRS / TOTW)     // 5 pairs per wave (exact)

// x[p,n,u] = b[p,u] + f0*wp0 + f1*wp1 + f2*wp2 + f3*wp3  (per lane = unit)
// wp folds W rows: wp0=W0+W4+W7, wp1=W1+W5+W8, wp2=W2+W6, wp3=W3
// b = -(m0*W4 + m1*W5 + m2*W6 + cx*W7 + cy*W8)
// sg = sign(gamma[u]) folded into weights: chain yields x' = sg*x, track max(x').
// Single cooperative kernel: phase1 per-pillar extremes in REGISTERS + BN
// partials; grid.sync; blocks 0..63 finalize scale/shift; grid.sync; apply.

__global__ __launch_bounds__(256, 4)
void pfn_all(const float* __restrict__ feat,
             const int*   __restrict__ nvox,
             const int*   __restrict__ coors,
             const float* __restrict__ Wm,
             const float* __restrict__ gamma,
             const float* __restrict__ beta,
             float*       __restrict__ out,
             float*       __restrict__ partials,
             float*       __restrict__ ss)
{
    __shared__ float  ps[WPB][128];
    __shared__ double sS[256], sQ[256];

    const int tid  = threadIdx.x;
    const int lane = tid & 63;
    const int wave = __builtin_amdgcn_readfirstlane(tid >> 6);   // provably uniform
    const int gwave = blockIdx.x * WPB + wave;

    const float sg  = (gamma[lane] >= 0.f) ? 1.f : -1.f;
    const float w4 = sg * Wm[4 * UNITS + lane], w5 = sg * Wm[5 * UNITS + lane];
    const float w6 = sg * Wm[6 * UNITS + lane], w7 = sg * Wm[7 * UNITS + lane];
    const float w8 = sg * Wm[8 * UNITS + lane];
    const float wp0 = sg * Wm[0 * UNITS + lane] + w4 + w7;
    const float wp1 = sg * Wm[1 * UNITS + lane] + w5 + w8;
    const float wp2 = sg * Wm[2 * UNITS + lane] + w6;
    const float wp3 = sg * Wm[3 * UNITS + lane];

    float extA[PPW], extB[PPW];          // static indices only (full unroll)
    unsigned padm = 0;                   // uniform -> lives in SGPR
    float lsum = 0.f, lsq = 0.f;         // sums of x' = sg*x

    #pragma unroll
    for (int it = 0; it < PPW; ++it) {
        const int pair = it * TOTW + gwave;   // uniform
        const int p0 = pair * 2;              // uniform

        // vector load of both pillars' points (1 KB/wave, coalesced) for means
        const float4 f4 = *reinterpret_cast<const float4*>(feat + (size_t)pair * 256 + lane * 4);
        float sx = f4.x, sy = f4.y, sz = f4.z;
        #pragma unroll
        for (int off = 1; off < 32; off <<= 1) {
            sx += __shfl_xor(sx, off);
            sy += __shfl_xor(sy, off);
            sz += __shfl_xor(sz, off);
        }

        // scalar metadata (uniform addresses -> s_load)
        int nvA = nvox[p0], nvB = nvox[p0 + 1];
        nvA = nvA < 1 ? 1 : (nvA > NPTS ? NPTS : nvA);
        nvB = nvB < 1 ? 1 : (nvB > NPTS ? NPTS : nvB);
        padm |= (nvA < NPTS ? 1u : 0u) << (2 * it);
        padm |= (nvB < NPTS ? 1u : 0u) << (2 * it + 1);
        const float cxA = (float)coors[p0 * 4 + 3] * 0.2f + 0.1f;
        const float cyA = (float)coors[p0 * 4 + 2] * 0.2f + (-39.9f);
        const float cxB = (float)coors[p0 * 4 + 7] * 0.2f + 0.1f;
        const float cyB = (float)coors[p0 * 4 + 6] * 0.2f + (-39.9f);
        const float iA  = 1.f / (float)nvA,  iB  = 1.f / (float)nvB;
        const float mA0 = __shfl(sx, 0)  * iA, mA1 = __shfl(sy, 0)  * iA, mA2 = __shfl(sz, 0)  * iA;
        const float mB0 = __shfl(sx, 32) * iB, mB1 = __shfl(sy, 32) * iB, mB2 = __shfl(sz, 32) * iB;
        const float bA = -(mA0 * w4 + mA1 * w5 + mA2 * w6 + cxA * w7 + cyA * w8);
        const float bB = -(mB0 * w4 + mB1 * w5 + mB2 * w6 + cxB * w7 + cyB * w8);

        // uniform point bases: whole wave reads the same point -> scalar loads
        const float* fpA = feat + (size_t)p0 * 128;
        const float* fpB = fpA + 128;

        float mA = -3.4e38f, mB = -3.4e38f;
        const int nmin = nvA < nvB ? nvA : nvB;

        #pragma unroll 4
        for (int n = 0; n < nmin; ++n) {
            const float4 a  = *reinterpret_cast<const float4*>(fpA + n * 4);
            const float4 b4 = *reinterpret_cast<const float4*>(fpB + n * 4);
            const float xA = fmaf(a.x,  wp0, fmaf(a.y,  wp1, fmaf(a.z,  wp2, fmaf(a.w,  wp3, bA))));
            const float xB = fmaf(b4.x, wp0, fmaf(b4.y, wp1, fmaf(b4.z, wp2, fmaf(b4.w, wp3, bB))));
            lsum += xA; lsq = fmaf(xA, xA, lsq); mA = fmaxf(mA, xA);
            lsum += xB; lsq = fmaf(xB, xB, lsq); mB = fmaxf(mB, xB);
        }
        #pragma unroll 4
        for (int n = nmin; n < nvA; ++n) {       // at most one tail loop runs
            const float4 a = *reinterpret_cast<const float4*>(fpA + n * 4);
            const float xA = fmaf(a.x, wp0, fmaf(a.y, wp1, fmaf(a.z, wp2, fmaf(a.w, wp3, bA))));
            lsum += xA; lsq = fmaf(xA, xA, lsq); mA = fmaxf(mA, xA);
        }
        #pragma unroll 4
        for (int n = nmin; n < nvB; ++n) {
            const float4 b4 = *reinterpret_cast<const float4*>(fpB + n * 4);
            const float xB = fmaf(b4.x, wp0, fmaf(b4.y, wp1, fmaf(b4.z, wp2, fmaf(b4.w, wp3, bB))));
            lsum += xB; lsq = fmaf(xB, xB, lsq); mB = fmaxf(mB, xB);
        }

        extA[it] = sg * mA;
        extB[it] = sg * mB;
    }

    ps[wave][lane]      = sg * lsum;   // Σx = sg * Σx'
    ps[wave][64 + lane] = lsq;         // x'^2 == x^2
    __syncthreads();
    if (tid < 128)
        partials[blockIdx.x * 128 + tid] = ps[0][tid] + ps[1][tid] + ps[2][tid] + ps[3][tid];

    cg::this_grid().sync();

    // ---- finalize: blocks 0..63, one unit each ----
    if (blockIdx.x < UNITS) {
        const int u = blockIdx.x;
        double aS = 0.0, aQ = 0.0;
        for (int b = tid; b < GBLOCKS; b += 256) {
            aS += (double)partials[b * 128 + u];
            aQ += (double)partials[b * 128 + 64 + u];
        }
        sS[tid] = aS; sQ[tid] = aQ;
        __syncthreads();
        for (int s = 128; s > 0; s >>= 1) {
            if (tid < s) { sS[tid] += sS[tid + s]; sQ[tid] += sQ[tid + s]; }
            __syncthreads();
        }
        if (tid == 0) {
            const double inv_pn = 1.0 / ((double)PTOT * (double)NPTS);
            const double mean = sS[0] * inv_pn;
            const double var  = sQ[0] * inv_pn - mean * mean;
            const float scale = gamma[u] * (float)(1.0 / sqrt(var + 1e-3));
            const float shift = beta[u] - (float)mean * scale;
            ss[u]      = scale;
            ss[64 + u] = shift;
        }
    }

    cg::this_grid().sync();

    // ---- apply from registers ----
    const float scale = ss[lane], shift = ss[64 + lane];
    const float padc  = fmaxf(shift, 0.f);     // candidate from padded points (incl. relu floor)
    #pragma unroll
    for (int it = 0; it < PPW; ++it) {
        const int pair = it * TOTW + gwave;
        const size_t p0 = (size_t)pair * 2;
        const float fA = ((padm >> (2 * it)) & 1u) ? padc : 0.f;
        const float fB = ((padm >> (2 * it + 1)) & 1u) ? padc : 0.f;
        out[p0 * UNITS + lane]       = fmaxf(fmaf(extA[it], scale, shift), fA);
        out[(p0 + 1) * UNITS + lane] = fmaxf(fmaf(extB[it], scale, shift), fB);
    }
}

extern "C" void kernel_launch(void* const* d_in, const int* in_sizes, int n_in,
                              void* d_out, int out_size, void* d_ws, size_t ws_size,
                              hipStream_t stream)
{
    const float* feat  = (const float*)d_in[0];
    const int*   nvox  = (const int*)d_in[1];
    const int*   coors = (const int*)d_in[2];
    const float* Wm    = (const float*)d_in[3];
    const float* gamma = (const float*)d_in[4];
    const float* beta  = (const float*)d_in[5];
    float* out = (float*)d_out;

    float* partials = (float*)d_ws;                        // GBLOCKS*128 floats = 512 KB
    float* ss       = partials + (size_t)GBLOCKS * 128;    // 128 floats

    void* args[] = { (void*)&feat, (void*)&nvox, (void*)&coors, (void*)&Wm,
                     (void*)&gamma, (void*)&beta, (void*)&out,
                     (void*)&partials, (void*)&ss };
    hipLaunchCooperativeKernel(reinterpret_cast<void*>(pfn_all),
                               dim3(GBLOCKS), dim3(256), args, 0, stream);
}

// Round 6
// 83.565 us; speedup vs baseline: 2.8882x; 2.8882x over previous
//
#include <hip/hip_runtime.h>
#include <math.h>

#define NPTS    32
#define UNITS   64
#define PTOT    40000
#define NPAIRS  (PTOT / 2)          // 20000
#define SBLOCKS 2500
#define WPB     4                   // waves per block (256 threads)
#define TOTW    (SBLOCKS * WPB)     // 10000 waves
#define PPW     (NPAIRS / TOTW)     // 2 pairs per wave (exact)

// x[p,n,u] = b[p,u] + f0*wp0 + f1*wp1 + f2*wp2 + f3*wp3  (per lane = unit)
// wp folds W rows: wp0=W0+W4+W7, wp1=W1+W5+W8, wp2=W2+W6, wp3=W3
// b = -(m0*W4 + m1*W5 + m2*W6 + cx*W7 + cy*W8)
// sg = sign(gamma[u]) folded into weights: chain yields x' = sg*x, track max(x').
// Point broadcast via v_readlane from the already-loaded f4 registers:
// inner loop is PURE VALU (no LDS, no s_load, no global loads).

__device__ __forceinline__ float rl(float v, int srclane) {
    return __int_as_float(__builtin_amdgcn_readlane(__float_as_int(v), srclane));
}

__global__ __launch_bounds__(256)
void pfn_main(const float* __restrict__ feat,
              const int*   __restrict__ nvox,
              const int*   __restrict__ coors,
              const float* __restrict__ Wm,
              const float* __restrict__ gamma,
              float*       __restrict__ xext,
              float*       __restrict__ accum)
{
    __shared__ float ps[WPB][128];

    const int tid  = threadIdx.x;
    const int lane = tid & 63;
    const int wave = __builtin_amdgcn_readfirstlane(tid >> 6);
    const int gwave = blockIdx.x * WPB + wave;

    const float sg  = (gamma[lane] >= 0.f) ? 1.f : -1.f;
    const float w4 = sg * Wm[4 * UNITS + lane], w5 = sg * Wm[5 * UNITS + lane];
    const float w6 = sg * Wm[6 * UNITS + lane], w7 = sg * Wm[7 * UNITS + lane];
    const float w8 = sg * Wm[8 * UNITS + lane];
    const float wp0 = sg * Wm[0 * UNITS + lane] + w4 + w7;
    const float wp1 = sg * Wm[1 * UNITS + lane] + w5 + w8;
    const float wp2 = sg * Wm[2 * UNITS + lane] + w6;
    const float wp3 = sg * Wm[3 * UNITS + lane];

    float lsum = 0.f, lsq = 0.f;   // sums of x' = sg*x

    #pragma unroll
    for (int it = 0; it < PPW; ++it) {
        const int pair = it * TOTW + gwave;   // uniform
        const int p0 = pair * 2;              // uniform

        // coalesced load: lane 0..31 -> pillar A's 32 points, 32..63 -> pillar B
        const float4 f4 = *reinterpret_cast<const float4*>(feat + (size_t)pair * 256 + lane * 4);

        // per-half xyz sums over all 32 raw points (reference sums unmasked)
        float sx = f4.x, sy = f4.y, sz = f4.z;
        #pragma unroll
        for (int off = 1; off < 32; off <<= 1) {
            sx += __shfl_xor(sx, off);
            sy += __shfl_xor(sy, off);
            sz += __shfl_xor(sz, off);
        }

        int nvA = nvox[p0], nvB = nvox[p0 + 1];       // uniform -> s_load
        nvA = nvA < 1 ? 1 : (nvA > NPTS ? NPTS : nvA);
        nvB = nvB < 1 ? 1 : (nvB > NPTS ? NPTS : nvB);
        const float cxA = (float)coors[p0 * 4 + 3] * 0.2f + 0.1f;
        const float cyA = (float)coors[p0 * 4 + 2] * 0.2f + (-39.9f);
        const float cxB = (float)coors[p0 * 4 + 7] * 0.2f + 0.1f;
        const float cyB = (float)coors[p0 * 4 + 6] * 0.2f + (-39.9f);
        const float iA  = 1.f / (float)nvA,  iB  = 1.f / (float)nvB;
        const float mA0 = rl(sx, 0)  * iA, mA1 = rl(sy, 0)  * iA, mA2 = rl(sz, 0)  * iA;
        const float mB0 = rl(sx, 32) * iB, mB1 = rl(sy, 32) * iB, mB2 = rl(sz, 32) * iB;
        const float bA = -(mA0 * w4 + mA1 * w5 + mA2 * w6 + cxA * w7 + cyA * w8);
        const float bB = -(mB0 * w4 + mB1 * w5 + mB2 * w6 + cxB * w7 + cyB * w8);

        float mA = -3.4e38f, mB = -3.4e38f;
        const int nmin = nvA < nvB ? nvA : nvB;

        #pragma unroll 4
        for (int n = 0; n < nmin; ++n) {              // pure VALU: readlane broadcast
            const float aX = rl(f4.x, n),      aY = rl(f4.y, n);
            const float aZ = rl(f4.z, n),      aW = rl(f4.w, n);
            const float bX = rl(f4.x, n + 32), bY = rl(f4.y, n + 32);
            const float bZ = rl(f4.z, n + 32), bW = rl(f4.w, n + 32);
            const float xA = fmaf(aX, wp0, fmaf(aY, wp1, fmaf(aZ, wp2, fmaf(aW, wp3, bA))));
            const float xB = fmaf(bX, wp0, fmaf(bY, wp1, fmaf(bZ, wp2, fmaf(bW, wp3, bB))));
            lsum += xA; lsq = fmaf(xA, xA, lsq); mA = fmaxf(mA, xA);
            lsum += xB; lsq = fmaf(xB, xB, lsq); mB = fmaxf(mB, xB);
        }
        #pragma unroll 4
        for (int n = nmin; n < nvA; ++n) {            // at most one tail loop runs
            const float aX = rl(f4.x, n), aY = rl(f4.y, n);
            const float aZ = rl(f4.z, n), aW = rl(f4.w, n);
            const float xA = fmaf(aX, wp0, fmaf(aY, wp1, fmaf(aZ, wp2, fmaf(aW, wp3, bA))));
            lsum += xA; lsq = fmaf(xA, xA, lsq); mA = fmaxf(mA, xA);
        }
        #pragma unroll 4
        for (int n = nmin; n < nvB; ++n) {
            const float bX = rl(f4.x, n + 32), bY = rl(f4.y, n + 32);
            const float bZ = rl(f4.z, n + 32), bW = rl(f4.w, n + 32);
            const float xB = fmaf(bX, wp0, fmaf(bY, wp1, fmaf(bZ, wp2, fmaf(bW, wp3, bB))));
            lsum += xB; lsq = fmaf(xB, xB, lsq); mB = fmaxf(mB, xB);
        }

        xext[(size_t)p0 * UNITS + lane]       = sg * mA;
        xext[(size_t)(p0 + 1) * UNITS + lane] = sg * mB;
    }

    ps[wave][lane]      = sg * lsum;   // Σx = sg * Σx'
    ps[wave][64 + lane] = lsq;         // x'^2 == x^2
    __syncthreads();
    if (tid < 128) {
        const float v = ps[0][tid] + ps[1][tid] + ps[2][tid] + ps[3][tid];
        atomicAdd(&accum[tid], v);     // device-scope; 128 addresses, end-of-block
    }
}

// Apply: per-block inline BN finalize from the 128-float accumulator, then
// streaming out[p,u] = max(scale*ext+shift, [nv<32 ? max(shift,0) : 0]).
#define CBLOCKS 2500   // 2500*256 threads * 1 float4 = 2,560,000 floats exactly

__global__ __launch_bounds__(256)
void pfn_apply(const float*  __restrict__ accum,
               const float*  __restrict__ gamma,
               const float*  __restrict__ beta,
               const float4* __restrict__ xext,
               const int*    __restrict__ nvox,
               float4*       __restrict__ out)
{
    __shared__ __align__(16) float s_sc[64], s_sh[64];
    const int t = threadIdx.x;
    if (t < 64) {
        const float INV_PN = 1.0f / (float)(PTOT * NPTS);
        const float S = accum[t], Q = accum[64 + t];
        const float mean  = S * INV_PN;
        const float var   = Q * INV_PN - mean * mean;
        const float scale = gamma[t] * rsqrtf(var + 1e-3f);
        s_sc[t] = scale;
        s_sh[t] = beta[t] - mean * scale;
    }
    __syncthreads();

    const int i  = blockIdx.x * 256 + t;     // float4 index
    const int u0 = (i & 15) * 4;             // first unit of this quad
    const int p  = i >> 4;                   // pillar
    const float4 sc = *reinterpret_cast<const float4*>(&s_sc[u0]);
    const float4 sh = *reinterpret_cast<const float4*>(&s_sh[u0]);
    const float4 e  = xext[i];
    const bool pad  = nvox[p] < NPTS;
    float4 o;
    o.x = fmaxf(fmaf(e.x, sc.x, sh.x), pad ? fmaxf(sh.x, 0.f) : 0.f);
    o.y = fmaxf(fmaf(e.y, sc.y, sh.y), pad ? fmaxf(sh.y, 0.f) : 0.f);
    o.z = fmaxf(fmaf(e.z, sc.z, sh.z), pad ? fmaxf(sh.z, 0.f) : 0.f);
    o.w = fmaxf(fmaf(e.w, sc.w, sh.w), pad ? fmaxf(sh.w, 0.f) : 0.f);
    out[i] = o;
}

extern "C" void kernel_launch(void* const* d_in, const int* in_sizes, int n_in,
                              void* d_out, int out_size, void* d_ws, size_t ws_size,
                              hipStream_t stream)
{
    const float* feat  = (const float*)d_in[0];
    const int*   nvox  = (const int*)d_in[1];
    const int*   coors = (const int*)d_in[2];
    const float* Wm    = (const float*)d_in[3];
    const float* gamma = (const float*)d_in[4];
    const float* beta  = (const float*)d_in[5];
    float* out = (float*)d_out;

    float* xext  = (float*)d_ws;                       // P*U floats = 10.24 MB
    float* accum = xext + (size_t)PTOT * UNITS;        // 128 floats (sum, sumsq)

    hipMemsetAsync(accum, 0, 128 * sizeof(float), stream);   // ws is poisoned, not re-zeroed
    pfn_main<<<SBLOCKS, 256, 0, stream>>>(feat, nvox, coors, Wm, gamma, xext, accum);
    pfn_apply<<<CBLOCKS, 256, 0, stream>>>(accum, gamma, beta,
                                           (const float4*)xext, nvox, (float4*)out);
}